// Round 13
// baseline (143.003 us; speedup 1.0000x reference)
//
#include <hip/hip_runtime.h>
#include <hip/hip_bf16.h>

#define BB 8
#define NN 2000
#define VV 2000
#define KK 100
#define EMB 128
#define PENALTY -1e9f
#define NBIN 512            // tracked bins; bin = v*2048 clamped to 511
#define BINSCALE 2048.0f
#define CAP 200
#define XPAD 224            // 201 padded to 7*32
#define SMALLTHR (255.0f / 2048.0f)
#define NWPACK 212
#define TOPKB (BB * NN / 4)  // 4000 topk blocks (wave per row)

typedef __attribute__((ext_vector_type(8))) short short8;
typedef __attribute__((ext_vector_type(4))) float f32x4;

#define WB() __builtin_amdgcn_wave_barrier()

__device__ __forceinline__ unsigned short bf16rne(float f) {
    unsigned u = __float_as_uint(f);
    u += 0x7FFF + ((u >> 16) & 1);
    return (unsigned short)(u >> 16);
}
__device__ __forceinline__ float bf2f(unsigned short s) {
    return __uint_as_float((unsigned)s << 16);
}

// iterate a lane's 32 values; fv = value, e = global element index, ci/j slot
#define FORALL_VALS(BODY)                                                    \
    _Pragma("unroll") for (int ci = 0; ci < 8; ++ci) {                       \
        { const int j = 0; const float fv = v4[ci].x; const int e = (ci * 64 + lane) * 4 + 0; BODY } \
        { const int j = 1; const float fv = v4[ci].y; const int e = (ci * 64 + lane) * 4 + 1; BODY } \
        { const int j = 2; const float fv = v4[ci].z; const int e = (ci * 64 + lane) * 4 + 2; BODY } \
        { const int j = 3; const float fv = v4[ci].w; const int e = (ci * 64 + lane) * 4 + 3; BODY } \
    }

// ---------------------------------------------------------------------------
// Kernel 1 (merged): blocks [0,NWPACK) pack weights (+ block 0 zeroes part);
// blocks [NWPACK, +4000) run wave-per-row exact top-K (ascending, ties by
// index). Prefilter (count < 255/2048 via shfl) -> ~12.5% of values hit the
// LDS histogram; bins byte-cached in regs. Packed u16 histogram. Exact radix
// fallback retained for adversarial rows.
// ---------------------------------------------------------------------------
__global__ __launch_bounds__(256) void topk_kernel(
    const float* __restrict__ dist, const float* __restrict__ scale,
    unsigned short* __restrict__ xin, unsigned short* __restrict__ sdist,
    unsigned short* __restrict__ idxb,
    const float* __restrict__ w1, const float* __restrict__ w2,
    const float* __restrict__ w3, const float* __restrict__ w4,
    unsigned short* __restrict__ pw1, unsigned short* __restrict__ pw2,
    unsigned short* __restrict__ pw3, unsigned short* __restrict__ pw4,
    float* __restrict__ part)
{
    __shared__ __align__(16) unsigned hist[4][NBIN / 2];   // packed 2xu16
    __shared__ __align__(16) unsigned snap[4][NBIN / 2];   // packed snapshot
    __shared__ unsigned long long comp[4][CAP];
    __shared__ unsigned long long comp2[4][KK];
    __shared__ int sh_cnt[4], sh_ntie[4], sh_kth[4];
    __shared__ unsigned sh_pref[4];
    __shared__ int sh_tie[4][64];

    const int t = threadIdx.x;

    if (blockIdx.x < NWPACK) {
        // ---------------- weight packing (+ part zero in block 0) ----------
        const int bt = blockIdx.x;
        if (bt == 0) {
#pragma unroll
            for (int i = 0; i < 16; ++i) part[i * 256 + t] = 0.f;
        }
        for (int e = t; e < 512; e += 256) {
            int lane = e >> 3, j = e & 7;
            int kk = ((lane >> 4) << 3) + j;
            int nn = lane & 15;
            if (bt < 56) {
                int kt = bt >> 3, nt = bt & 7;
                int k = kt * 32 + kk, n = nt * 16 + nn;
                float f = (k < 201) ? w1[k * 128 + n] : 0.f;
                pw1[bt * 512 + e] = bf16rne(f);
            } else if (bt < 120) {
                int bb = bt - 56, kt = bb >> 4, nt = bb & 15;
                pw2[bb * 512 + e] = bf16rne(w2[(kt * 32 + kk) * 256 + nt * 16 + nn]);
            } else if (bt < 184) {
                int bb = bt - 120, kt = bb >> 3, nt = bb & 7;
                pw3[bb * 512 + e] = bf16rne(w3[(kt * 32 + kk) * 128 + nt * 16 + nn]);
            } else {
                int bb = bt - 184, kt = bb / 7, nt = bb % 7;
                int n = nt * 16 + nn;
                float f = (n < 100) ? w4[(kt * 32 + kk) * 100 + n] : 0.f;
                pw4[bb * 512 + e] = bf16rne(f);
            }
        }
        return;
    }

    const int w = t >> 6, lane = t & 63;
    const int row = (blockIdx.x - NWPACK) * 4 + w;
    const float4* d4 = (const float4*)(dist + (size_t)row * VV);

    // 32 values/lane, coalesced (sentinel 2.0 > all real values -> clamp bin)
    float4 v4[8];
#pragma unroll
    for (int c = 0; c < 7; ++c) v4[c] = d4[c * 64 + lane];
    v4[7] = (lane < 52) ? d4[448 + lane] : make_float4(2.f, 2.f, 2.f, 2.f);

    // prefilter: count values < SMALLTHR across the wave
    int nsmall = 0;
    FORALL_VALS({ nsmall += (fv < SMALLTHR) ? 1 : 0; (void)e; (void)j; (void)ci; });
#pragma unroll
    for (int off = 1; off < 64; off <<= 1) nsmall += __shfl_xor(nsmall, off);
    const bool fast = (nsmall >= KK);

    // zero my 4 packed words (256 words = 512 u16 bins)
#pragma unroll
    for (int i = 0; i < 4; ++i) hist[w][lane * 4 + i] = 0u;
    if (lane == 0) { sh_cnt[w] = 0; sh_ntie[w] = 0; }
    WB();

    // histogram + byte-cache bins (fast: only bins < 255 counted)
    unsigned bcache[8];
    FORALL_VALS({
        int b = (int)(fv * BINSCALE);
        b = b < 0 ? 0 : (b > NBIN - 1 ? NBIN - 1 : b);
        int bb = b > 255 ? 255 : b;
        if (j == 0) bcache[ci] = (unsigned)bb;
        else bcache[ci] |= (unsigned)bb << (8 * j);
        bool doh = fast ? (b < 255) : (b < NBIN - 1);
        if (doh) atomicAdd(&hist[w][b >> 1], 1u << ((b & 1) << 4));
        (void)e;
    });
    WB();

    // prefix scan: lane owns packed words [4*lane, 4*lane+4) = bins [8l,8l+8)
    unsigned cw0 = hist[w][lane * 4 + 0];
    unsigned cw1 = hist[w][lane * 4 + 1];
    unsigned cw2 = hist[w][lane * 4 + 2];
    unsigned cw3 = hist[w][lane * 4 + 3];
    unsigned tot = (cw0 & 0xFFFFu) + (cw0 >> 16) + (cw1 & 0xFFFFu) + (cw1 >> 16) +
                   (cw2 & 0xFFFFu) + (cw2 >> 16) + (cw3 & 0xFFFFu) + (cw3 >> 16);
    unsigned incl = tot;
#pragma unroll
    for (int off = 1; off < 64; off <<= 1) {
        unsigned v = __shfl_up(incl, (unsigned)off);
        if (lane >= off) incl += v;
    }
    unsigned run = incl - tot;   // exclusive start of my 8 bins

    int myBt = -1, myM = 0;
#pragma unroll
    for (int i = 0; i < 4; ++i) {
        unsigned cwi = (i == 0) ? cw0 : (i == 1) ? cw1 : (i == 2) ? cw2 : cw3;
        unsigned c0 = cwi & 0xFFFFu, c1 = cwi >> 16;
        unsigned st0 = run, st1 = run + c0;
        if (myBt < 0 && st0 < KK && st0 + c0 >= KK) {
            myBt = lane * 8 + 2 * i; myM = (int)(st0 + c0);
        }
        if (myBt < 0 && st1 < KK && st1 + c1 >= KK) {
            myBt = lane * 8 + 2 * i + 1; myM = (int)(st1 + c1);
        }
        unsigned packed = st0 | (st1 << 16);
        hist[w][lane * 4 + i] = packed;
        snap[w][lane * 4 + i] = packed;
        run = st1 + c1;
    }
    WB();

    unsigned long long bl = __ballot(myBt >= 0);
    int Bt, m;
    if (bl != 0ull) {
        int src = __ffsll(bl) - 1;
        Bt = __shfl(myBt, src);
        m = __shfl(myM, src);
    } else {
        Bt = NBIN - 1;
        m = 100000;
    }

    if (m <= CAP) {
        // ---- bin-scatter winners into comp (packed atomic slot) ----
        FORALL_VALS({
            int b;
            if (fast) b = (int)((bcache[ci] >> (8 * j)) & 255u);
            else {
                b = (int)(fv * BINSCALE);
                b = b < 0 ? 0 : (b > NBIN - 1 ? NBIN - 1 : b);
            }
            if (b <= Bt) {
                int sh = (b & 1) << 4;
                unsigned old = atomicAdd(&hist[w][b >> 1], 1u << sh);
                int slot = (int)((old >> sh) & 0xFFFFu);
                comp[w][slot] =
                    ((unsigned long long)__float_as_uint(fv) << 32) | (unsigned)e;
            }
        });
        WB();
        // ---- rank pass over compacted slots (<= 4 per lane) ----
        for (int o = lane; o < m; o += 64) {
            unsigned long long key = comp[w][o];
            float fv = __uint_as_float((unsigned)(key >> 32));
            int b = (int)(fv * BINSCALE);
            b = b < 0 ? 0 : (b > NBIN - 1 ? NBIN - 1 : b);
            int sh = (b & 1) << 4;
            unsigned e0 = (hist[w][b >> 1] >> sh) & 0xFFFFu;
            unsigned s0 = (snap[w][b >> 1] >> sh) & 0xFFFFu;
            int r = (int)s0;
            for (unsigned s = s0; s < e0; ++s) r += (comp[w][s] < key);
            if (r < KK) comp2[w][r] = key;
        }
    } else {
        // ---------- rare exact fallback: radix-refine threshold bucket ------
        FORALL_VALS({
            int b = (int)(fv * BINSCALE);
            b = b < 0 ? 0 : (b > NBIN - 1 ? NBIN - 1 : b);
            if (b < Bt) {
                int pos = atomicAdd(&sh_cnt[w], 1);
                if (pos < CAP)
                    comp[w][pos] =
                        ((unsigned long long)__float_as_uint(fv) << 32) | (unsigned)e;
            }
            (void)j; (void)ci;
        });
        WB();
        int nless = sh_cnt[w];
        if (lane == 0) { sh_pref[w] = 0u; sh_kth[w] = KK - nless; }
        WB();
        for (int p = 0; p < 4; ++p) {
#pragma unroll
            for (int i = 0; i < 4; ++i) hist[w][lane * 4 + i] = 0u;
            WB();
            const int shift = 24 - 8 * p;
            const unsigned pref = sh_pref[w];
            FORALL_VALS({
                int b = (int)(fv * BINSCALE);
                b = b < 0 ? 0 : (b > NBIN - 1 ? NBIN - 1 : b);
                if (b == Bt) {
                    unsigned k = __float_as_uint(fv);
                    bool ok = (p == 0) || ((k >> (shift + 8)) == pref);
                    if (ok) atomicAdd(&hist[w][(k >> shift) & 255u], 1u);
                }
                (void)e; (void)j; (void)ci;
            });
            WB();
            if (lane == 0) {
                int kth = sh_kth[w];
                unsigned cum = 0;
                int b = 0;
                for (; b < 256; ++b) {
                    unsigned cc = hist[w][b];
                    if (cum + cc >= (unsigned)kth) break;
                    cum += cc;
                }
                sh_pref[w] = (pref << 8) | (unsigned)b;
                sh_kth[w] = kth - (int)cum;
            }
            WB();
        }
        const unsigned T = sh_pref[w];
        const int need2 = sh_kth[w];
        FORALL_VALS({
            int b = (int)(fv * BINSCALE);
            b = b < 0 ? 0 : (b > NBIN - 1 ? NBIN - 1 : b);
            if (b == Bt) {
                unsigned k = __float_as_uint(fv);
                if (k < T) {
                    int pos = atomicAdd(&sh_cnt[w], 1);
                    if (pos < CAP)
                        comp[w][pos] = ((unsigned long long)k << 32) | (unsigned)e;
                } else if (k == T) {
                    int q = atomicAdd(&sh_ntie[w], 1);
                    if (q < 64) sh_tie[w][q] = e;
                }
            }
            (void)j; (void)ci;
        });
        WB();
        if (lane == 0) {
            int nl2 = sh_cnt[w];
            int nt = sh_ntie[w] < 64 ? sh_ntie[w] : 64;
            for (int i = 1; i < nt; ++i) {
                int v = sh_tie[w][i], j2 = i - 1;
                while (j2 >= 0 && sh_tie[w][j2] > v) {
                    sh_tie[w][j2 + 1] = sh_tie[w][j2];
                    --j2;
                }
                sh_tie[w][j2 + 1] = v;
            }
            for (int i = 0; i < need2; ++i)
                comp[w][nl2 + i] =
                    ((unsigned long long)T << 32) | (unsigned)sh_tie[w][i];
            sh_cnt[w] = nl2 + need2;
        }
        WB();
        const int mm = sh_cnt[w];   // == KK
        for (int o = lane; o < mm; o += 64) {
            unsigned long long key = comp[w][o];
            int r = 0;
            for (int j2 = 0; j2 < mm; ++j2) {
                unsigned long long cj = comp[w][j2];
                r += (cj < key) || (cj == key && j2 < o);
            }
            if (r < KK) comp2[w][r] = key;
        }
    }
    WB();

    // ---- epilogue from comp2 (sorted ascending, rank = index) ----
    const float Tf = __uint_as_float((unsigned)(comp2[w][KK - 1] >> 32));
    const float invT = 1.0f / Tf;
    for (int o = lane; o < KK; o += 64) {
        unsigned long long c = comp2[w][o];
        unsigned kbits = (unsigned)(c >> 32);
        int id = (int)(c & 0xFFFFFFFFu);
        unsigned short nb = bf16rne(__uint_as_float(kbits) * invT);
        xin[(size_t)row * XPAD + o] = nb;
        sdist[(size_t)row * KK + o] = nb;
        idxb[(size_t)row * KK + o] = (unsigned short)id;
    }
    if (lane == 0) xin[(size_t)row * XPAD + 200] = bf16rne(scale[row]);
    else if (lane < 24) xin[(size_t)row * XPAD + 200 + lane] = 0;  // zero pad
}

// ---------------------------------------------------------------------------
// Kernel 1b: theta gather, full-throughput (one (row,k) per thread).
// ---------------------------------------------------------------------------
__global__ __launch_bounds__(256) void gather_kernel(
    const float* __restrict__ theta, const unsigned short* __restrict__ idxb,
    unsigned short* __restrict__ xin)
{
    const int i = blockIdx.x * 256 + threadIdx.x;   // exact: M*KK = 6250*256
    const int row = i / KK;
    const int k = i - row * KK;
    const int id = (int)idxb[i];
    float v = theta[(size_t)row * VV + id];
    xin[(size_t)row * XPAD + 100 + k] = bf16rne(v);
}

// ---------------------------------------------------------------------------
// Kernel 2: fused layers 1+2 via MFMA + InstanceNorm partial sums.
// Block = 64 rows, 4 waves. Per-(batch,channel) sum/sumsq reduced in an LDS
// overlay on dead c1s, then one global atomicAdd per channel into part[].
// ---------------------------------------------------------------------------
__global__ __launch_bounds__(256) void fused12_mfma(
    const unsigned short* __restrict__ xin, const unsigned short* __restrict__ pw1,
    const float* __restrict__ b1, const unsigned short* __restrict__ pw2,
    const float* __restrict__ b2, unsigned short* __restrict__ h,
    float* __restrict__ part)
{
    __shared__ __align__(16) unsigned short c1s[64][136];
    const int t = threadIdx.x;
    const int w = t >> 6, l = t & 63;
    const int m0 = blockIdx.x * 64;
    const int lr = l & 15, lg = l >> 4;

    f32x4 acc[8] = {};
    const short8* arow = (const short8*)(xin + (size_t)(m0 + 16 * w + lr) * XPAD);
    const short8* pw1v = (const short8*)pw1;
#pragma unroll
    for (int kt = 0; kt < 7; ++kt) {
        short8 a = arow[kt * 4 + lg];
#pragma unroll
        for (int nt = 0; nt < 8; ++nt) {
            short8 b = pw1v[(kt * 8 + nt) * 64 + l];
            acc[nt] = __builtin_amdgcn_mfma_f32_16x16x32_bf16(a, b, acc[nt], 0, 0, 0);
        }
    }
#pragma unroll
    for (int nt = 0; nt < 8; ++nt) {
        int col = nt * 16 + lr;
        float bb = b1[col];
#pragma unroll
        for (int r = 0; r < 4; ++r) {
            float v = fmaxf(acc[nt][r] + bb, 0.f);
            c1s[16 * w + lg * 4 + r][col] = bf16rne(v);
        }
    }
    __syncthreads();

    f32x4 acc2[16] = {};
    const short8* pw2v = (const short8*)pw2;
#pragma unroll
    for (int kt = 0; kt < 4; ++kt) {
        short8 a = *(const short8*)&c1s[16 * w + lr][kt * 32 + lg * 8];
#pragma unroll
        for (int nt = 0; nt < 16; ++nt) {
            short8 b = pw2v[(kt * 16 + nt) * 64 + l];
            acc2[nt] = __builtin_amdgcn_mfma_f32_16x16x32_bf16(a, b, acc2[nt], 0, 0, 0);
        }
    }
    __syncthreads();                       // all c1s reads done -> overlay
    float* sums = (float*)c1s;             // [2][256][2] = 1024 floats
    for (int i = t; i < 1024; i += 256) sums[i] = 0.f;
    __syncthreads();

    const int batch0 = m0 / NN;
    const int bl = ((m0 + 16 * w + lg * 4) / NN) - batch0;   // 4 rows same batch
#pragma unroll
    for (int nt = 0; nt < 16; ++nt) {
        int col = nt * 16 + lr;
        float bb = b2[col];
        float s = 0.f, s2 = 0.f;
#pragma unroll
        for (int r = 0; r < 4; ++r) {
            float v = fmaxf(acc2[nt][r] + bb, 0.f);
            h[(size_t)(m0 + 16 * w + lg * 4 + r) * 256 + col] = bf16rne(v);
            s += v;
            s2 += v * v;
        }
        atomicAdd(&sums[(bl * 256 + col) * 2 + 0], s);
        atomicAdd(&sums[(bl * 256 + col) * 2 + 1], s2);
    }
    __syncthreads();
    {
        const int col = t;   // 0..255
        const bool strad = ((m0 + 63) / NN) != batch0;
        atomicAdd(&part[(batch0 * 256 + col) * 2 + 0], sums[col * 2 + 0]);
        atomicAdd(&part[(batch0 * 256 + col) * 2 + 1], sums[col * 2 + 1]);
        if (strad) {
            atomicAdd(&part[((batch0 + 1) * 256 + col) * 2 + 0],
                      sums[(256 + col) * 2 + 0]);
            atomicAdd(&part[((batch0 + 1) * 256 + col) * 2 + 1],
                      sums[(256 + col) * 2 + 1]);
        }
    }
}

// ---------------------------------------------------------------------------
// Kernel 3: fused layers 3+4 + STREAMING output write (bitmap + popcount).
// InstanceNorm finalize computed per-block from part[] into an LDS overlay
// on wpref (dead until after S2 -> lifetimes disjoint).
// ---------------------------------------------------------------------------
__global__ __launch_bounds__(256) void fused34_mfma(
    const unsigned short* __restrict__ h, const unsigned short* __restrict__ pw3,
    const float* __restrict__ b3, const unsigned short* __restrict__ pw4,
    const float* __restrict__ b4, const float* __restrict__ part,
    const float* __restrict__ gamma, const float* __restrict__ beta,
    const unsigned short* __restrict__ sdist,
    const unsigned short* __restrict__ idxb, float* __restrict__ out)
{
    __shared__ __align__(16) char uni[64 * 100 * 4];      // c1s / valbuf union
    __shared__ __align__(16) unsigned bm[64][64];          // 2048-bit bitmaps
    __shared__ __align__(16) unsigned short wpref[64][64]; // prefix / scl+shl
    unsigned short (*c1s)[136] = (unsigned short (*)[136])uni;
    float (*valbuf)[100] = (float (*)[100])uni;
    float* scl = (float*)wpref;           // [2][256] folded scale
    float* shl = scl + 512;               // [2][256] folded shift

    const int t = threadIdx.x;
    const int w = t >> 6, l = t & 63;
    const int m0 = blockIdx.x * 64;
    const int lr = l & 15, lg = l >> 4;
    const int batch0 = m0 / NN;
    const bool strad = ((m0 + 63) / NN) != batch0;

    // ---- InstanceNorm finalize (overlay on wpref; consumed in phase 1) ----
    {
        const int col = t;
        float g = gamma[col], be = beta[col];
        float s = part[(batch0 * 256 + col) * 2 + 0];
        float s2 = part[(batch0 * 256 + col) * 2 + 1];
        float mean = s * (1.0f / NN);
        float var = s2 * (1.0f / NN) - mean * mean;
        float sc = g * rsqrtf(var + 1e-5f);
        scl[col] = sc;
        shl[col] = be - mean * sc;
        if (strad) {
            s = part[((batch0 + 1) * 256 + col) * 2 + 0];
            s2 = part[((batch0 + 1) * 256 + col) * 2 + 1];
            mean = s * (1.0f / NN);
            var = s2 * (1.0f / NN) - mean * mean;
            sc = g * rsqrtf(var + 1e-5f);
            scl[256 + col] = sc;
            shl[256 + col] = be - mean * sc;
        }
    }

    // zero bitmaps
    for (int i = t; i < 64 * 64; i += 256) ((unsigned*)bm)[i] = 0u;
    __syncthreads();                                       // S1

    // build bitmaps from idxb (coalesced u16)
    for (int i = t; i < 64 * KK; i += 256) {
        int rrow = i / KK;
        int id = (int)idxb[(size_t)(m0 + rrow) * KK + (i - rrow * KK)];
        atomicOr(&bm[rrow][id >> 5], 1u << (id & 31));
    }

    const int myrow = m0 + 16 * w + lr;
    const int bl = (myrow / NN) - batch0;
    const int nbase = bl * 256;

    // phase 1: norm(h) @ w3, K=256, N=128 (affine from LDS scl/shl)
    f32x4 acc[8] = {};
    const short8* hrow = (const short8*)(h + (size_t)myrow * 256);
    const short8* pw3v = (const short8*)pw3;
#pragma unroll
    for (int kt = 0; kt < 8; ++kt) {
        int k0 = kt * 32 + lg * 8;
        short8 hv = hrow[kt * 4 + lg];
        short8 a;
#pragma unroll
        for (int i = 0; i < 8; ++i)
            a[i] = (short)bf16rne(fmaf(bf2f((unsigned short)hv[i]),
                                       scl[nbase + k0 + i], shl[nbase + k0 + i]));
#pragma unroll
        for (int nt = 0; nt < 8; ++nt) {
            short8 b = pw3v[(kt * 8 + nt) * 64 + l];
            acc[nt] = __builtin_amdgcn_mfma_f32_16x16x32_bf16(a, b, acc[nt], 0, 0, 0);
        }
    }
    __syncthreads();                                       // S2 (bitmap done)

    // word-popcount prefix per row (t<64: one row each) — overwrites scl/shl
    if (t < 64) {
        unsigned run = 0;
#pragma unroll
        for (int wd = 0; wd < 63; ++wd) {
            wpref[t][wd] = (unsigned short)run;
            run += (unsigned)__popc(bm[t][wd]);
        }
        wpref[t][63] = (unsigned short)run;
    }

#pragma unroll
    for (int nt = 0; nt < 8; ++nt) {
        int col = nt * 16 + lr;
        float bb = b3[col];
#pragma unroll
        for (int r = 0; r < 4; ++r) {
            float v = fmaxf(acc[nt][r] + bb, 0.f);
            c1s[16 * w + lg * 4 + r][col] = bf16rne(v);
        }
    }
    __syncthreads();                                       // S3

    // phase 2: @ w4, K=128, N=112 (cols 100..111 zero weights)
    f32x4 acc2[7] = {};
    const short8* pw4v = (const short8*)pw4;
#pragma unroll
    for (int kt = 0; kt < 4; ++kt) {
        short8 a = *(const short8*)&c1s[16 * w + lr][kt * 32 + lg * 8];
#pragma unroll
        for (int nt = 0; nt < 7; ++nt) {
            short8 b = pw4v[(kt * 7 + nt) * 64 + l];
            acc2[nt] = __builtin_amdgcn_mfma_f32_16x16x32_bf16(a, b, acc2[nt], 0, 0, 0);
        }
    }
    __syncthreads();                                       // S4 (c1s dead)

    // epilogue: +b4 - sdist(bf16), place into valbuf at index-order rank
#pragma unroll
    for (int nt = 0; nt < 7; ++nt) {
        int col = nt * 16 + lr;
        if (col < KK) {
            float bb = b4[col];
#pragma unroll
            for (int r = 0; r < 4; ++r) {
                int r4 = 16 * w + lg * 4 + r;
                int mrow = m0 + r4;
                float v = acc2[nt][r] + bb -
                          bf2f(sdist[(size_t)mrow * KK + col]);
                int id = (int)idxb[(size_t)mrow * KK + col];
                int wd = id >> 5;
                int irank = (int)wpref[r4][wd] +
                            __popc(bm[r4][wd] & ((1u << (id & 31)) - 1u));
                valbuf[r4][irank] = v;
            }
        }
    }
    __syncthreads();                                       // S5

    // streaming write: 64 rows x 500 float4, fully coalesced, no RFO
    for (int i = t; i < 64 * (VV / 4); i += 256) {
        int rrow = i / (VV / 4);
        int p = i - rrow * (VV / 4);
        int v0 = p * 4;
        unsigned word = bm[rrow][v0 >> 5];
        int sh = v0 & 31;
        int racc = (int)wpref[rrow][v0 >> 5] + __popc(word & ((1u << sh) - 1u));
        float4 o;
        unsigned b0 = (word >> sh) & 1u;
        o.x = b0 ? valbuf[rrow][racc] : PENALTY; racc += b0;
        unsigned b1_ = (word >> (sh + 1)) & 1u;
        o.y = b1_ ? valbuf[rrow][racc] : PENALTY; racc += b1_;
        unsigned b2_ = (word >> (sh + 2)) & 1u;
        o.z = b2_ ? valbuf[rrow][racc] : PENALTY; racc += b2_;
        unsigned b3_ = (word >> (sh + 3)) & 1u;
        o.w = b3_ ? valbuf[rrow][racc] : PENALTY;
        ((float4*)(out + (size_t)(m0 + rrow) * VV))[p] = o;
    }
}

extern "C" void kernel_launch(void* const* d_in, const int* in_sizes, int n_in,
                              void* d_out, int out_size, void* d_ws, size_t ws_size,
                              hipStream_t stream)
{
    const float* dist  = (const float*)d_in[0];
    const float* theta = (const float*)d_in[1];
    const float* scale = (const float*)d_in[2];
    const float* w1 = (const float*)d_in[3];
    const float* b1 = (const float*)d_in[4];
    const float* w2 = (const float*)d_in[5];
    const float* b2 = (const float*)d_in[6];
    const float* w3 = (const float*)d_in[7];
    const float* b3 = (const float*)d_in[8];
    const float* w4 = (const float*)d_in[9];
    const float* b4 = (const float*)d_in[10];
    const float* gamma = (const float*)d_in[11];
    const float* beta  = (const float*)d_in[12];
    float* out = (float*)d_out;

    const int M = BB * NN;  // 16000

    char* p = (char*)d_ws;
    unsigned short* xin   = (unsigned short*)p;     p += (size_t)M * XPAD * 2;
    unsigned short* h     = (unsigned short*)p;     p += (size_t)M * 256 * 2;
    unsigned short* sdist = (unsigned short*)p;     p += (size_t)M * KK * 2;
    unsigned short* idxb  = (unsigned short*)p;     p += (size_t)M * KK * 2;
    float* part  = (float*)p;                       p += 8 * 256 * 2 * 4;
    unsigned short* pw1 = (unsigned short*)p;       p += 56 * 512 * 2;
    unsigned short* pw2 = (unsigned short*)p;       p += 64 * 512 * 2;
    unsigned short* pw3 = (unsigned short*)p;       p += 64 * 512 * 2;
    unsigned short* pw4 = (unsigned short*)p;       p += 28 * 512 * 2;

    topk_kernel<<<NWPACK + TOPKB, 256, 0, stream>>>(
        dist, scale, xin, sdist, idxb,
        w1, w2, w3, w4, pw1, pw2, pw3, pw4, part);

    gather_kernel<<<(M * KK) / 256, 256, 0, stream>>>(theta, idxb, xin);

    fused12_mfma<<<M / 64, 256, 0, stream>>>(xin, pw1, b1, pw2, b2, h, part);

    fused34_mfma<<<M / 64, 256, 0, stream>>>(h, pw3, b3, pw4, b4, part,
                                             gamma, beta, sdist, idxb, out);
}

// Round 14
// 133.425 us; speedup vs baseline: 1.0718x; 1.0718x over previous
//
#include <hip/hip_runtime.h>
#include <hip/hip_bf16.h>

#define BB 8
#define NN 2000
#define VV 2000
#define KK 100
#define EMB 128
#define PENALTY -1e9f
#define NBIN 512            // tracked bins; bin = v*2048 clamped to 511
#define BINSCALE 2048.0f
#define CAP 200
#define XPAD 224            // 201 padded to 7*32
#define SMALLTHR (255.0f / 2048.0f)
#define NWPACK 212
#define TOPKB (BB * NN / 4)  // 4000 topk blocks (wave per row)

typedef __attribute__((ext_vector_type(8))) short short8;
typedef __attribute__((ext_vector_type(4))) float f32x4;

#define WB() __builtin_amdgcn_wave_barrier()

__device__ __forceinline__ unsigned short bf16rne(float f) {
    unsigned u = __float_as_uint(f);
    u += 0x7FFF + ((u >> 16) & 1);
    return (unsigned short)(u >> 16);
}
__device__ __forceinline__ float bf2f(unsigned short s) {
    return __uint_as_float((unsigned)s << 16);
}

// iterate a lane's 32 values; fv = value, e = global element index, ci/j slot
#define FORALL_VALS(BODY)                                                    \
    _Pragma("unroll") for (int ci = 0; ci < 8; ++ci) {                       \
        { const int j = 0; const float fv = v4[ci].x; const int e = (ci * 64 + lane) * 4 + 0; BODY } \
        { const int j = 1; const float fv = v4[ci].y; const int e = (ci * 64 + lane) * 4 + 1; BODY } \
        { const int j = 2; const float fv = v4[ci].z; const int e = (ci * 64 + lane) * 4 + 2; BODY } \
        { const int j = 3; const float fv = v4[ci].w; const int e = (ci * 64 + lane) * 4 + 3; BODY } \
    }

// ---------------------------------------------------------------------------
// Kernel 1 (merged): blocks [0,NWPACK) pack weights; blocks [NWPACK,+4000)
// run wave-per-row exact top-K (ascending, ties by index).
// Prefilter (count < 255/2048 via shfl) -> ~12.5% of values hit the LDS
// histogram; bins byte-cached in regs. Packed u16 histogram. Exact radix
// fallback retained for adversarial rows. sdist is NOT stored separately —
// fused34 reads the identical bf16 values from xin cols [0,100).
// ---------------------------------------------------------------------------
__global__ __launch_bounds__(256) void topk_kernel(
    const float* __restrict__ dist, const float* __restrict__ scale,
    unsigned short* __restrict__ xin, unsigned short* __restrict__ idxb,
    const float* __restrict__ w1, const float* __restrict__ w2,
    const float* __restrict__ w3, const float* __restrict__ w4,
    unsigned short* __restrict__ pw1, unsigned short* __restrict__ pw2,
    unsigned short* __restrict__ pw3, unsigned short* __restrict__ pw4)
{
    __shared__ __align__(16) unsigned hist[4][NBIN / 2];   // packed 2xu16
    __shared__ __align__(16) unsigned snap[4][NBIN / 2];   // packed snapshot
    __shared__ unsigned long long comp[4][CAP];
    __shared__ unsigned long long comp2[4][KK];
    __shared__ int sh_cnt[4], sh_ntie[4], sh_kth[4];
    __shared__ unsigned sh_pref[4];
    __shared__ int sh_tie[4][64];

    const int t = threadIdx.x;

    if (blockIdx.x < NWPACK) {
        // ---------------- weight packing ----------------
        const int bt = blockIdx.x;
        for (int e = t; e < 512; e += 256) {
            int lane = e >> 3, j = e & 7;
            int kk = ((lane >> 4) << 3) + j;
            int nn = lane & 15;
            if (bt < 56) {
                int kt = bt >> 3, nt = bt & 7;
                int k = kt * 32 + kk, n = nt * 16 + nn;
                float f = (k < 201) ? w1[k * 128 + n] : 0.f;
                pw1[bt * 512 + e] = bf16rne(f);
            } else if (bt < 120) {
                int bb = bt - 56, kt = bb >> 4, nt = bb & 15;
                pw2[bb * 512 + e] = bf16rne(w2[(kt * 32 + kk) * 256 + nt * 16 + nn]);
            } else if (bt < 184) {
                int bb = bt - 120, kt = bb >> 3, nt = bb & 7;
                pw3[bb * 512 + e] = bf16rne(w3[(kt * 32 + kk) * 128 + nt * 16 + nn]);
            } else {
                int bb = bt - 184, kt = bb / 7, nt = bb % 7;
                int n = nt * 16 + nn;
                float f = (n < 100) ? w4[(kt * 32 + kk) * 100 + n] : 0.f;
                pw4[bb * 512 + e] = bf16rne(f);
            }
        }
        return;
    }

    const int w = t >> 6, lane = t & 63;
    const int row = (blockIdx.x - NWPACK) * 4 + w;
    const float4* d4 = (const float4*)(dist + (size_t)row * VV);

    // 32 values/lane, coalesced (sentinel 2.0 > all real values -> clamp bin)
    float4 v4[8];
#pragma unroll
    for (int c = 0; c < 7; ++c) v4[c] = d4[c * 64 + lane];
    v4[7] = (lane < 52) ? d4[448 + lane] : make_float4(2.f, 2.f, 2.f, 2.f);

    // prefilter: count values < SMALLTHR across the wave
    int nsmall = 0;
    FORALL_VALS({ nsmall += (fv < SMALLTHR) ? 1 : 0; (void)e; (void)j; (void)ci; });
#pragma unroll
    for (int off = 1; off < 64; off <<= 1) nsmall += __shfl_xor(nsmall, off);
    const bool fast = (nsmall >= KK);

    // zero my 4 packed words (256 words = 512 u16 bins)
#pragma unroll
    for (int i = 0; i < 4; ++i) hist[w][lane * 4 + i] = 0u;
    if (lane == 0) { sh_cnt[w] = 0; sh_ntie[w] = 0; }
    WB();

    // histogram + byte-cache bins (fast: only bins < 255 counted)
    unsigned bcache[8];
    FORALL_VALS({
        int b = (int)(fv * BINSCALE);
        b = b < 0 ? 0 : (b > NBIN - 1 ? NBIN - 1 : b);
        int bb = b > 255 ? 255 : b;
        if (j == 0) bcache[ci] = (unsigned)bb;
        else bcache[ci] |= (unsigned)bb << (8 * j);
        bool doh = fast ? (b < 255) : (b < NBIN - 1);
        if (doh) atomicAdd(&hist[w][b >> 1], 1u << ((b & 1) << 4));
        (void)e;
    });
    WB();

    // prefix scan: lane owns packed words [4*lane, 4*lane+4) = bins [8l,8l+8)
    unsigned cw0 = hist[w][lane * 4 + 0];
    unsigned cw1 = hist[w][lane * 4 + 1];
    unsigned cw2 = hist[w][lane * 4 + 2];
    unsigned cw3 = hist[w][lane * 4 + 3];
    unsigned tot = (cw0 & 0xFFFFu) + (cw0 >> 16) + (cw1 & 0xFFFFu) + (cw1 >> 16) +
                   (cw2 & 0xFFFFu) + (cw2 >> 16) + (cw3 & 0xFFFFu) + (cw3 >> 16);
    unsigned incl = tot;
#pragma unroll
    for (int off = 1; off < 64; off <<= 1) {
        unsigned v = __shfl_up(incl, (unsigned)off);
        if (lane >= off) incl += v;
    }
    unsigned run = incl - tot;   // exclusive start of my 8 bins

    int myBt = -1, myM = 0;
#pragma unroll
    for (int i = 0; i < 4; ++i) {
        unsigned cwi = (i == 0) ? cw0 : (i == 1) ? cw1 : (i == 2) ? cw2 : cw3;
        unsigned c0 = cwi & 0xFFFFu, c1 = cwi >> 16;
        unsigned st0 = run, st1 = run + c0;
        if (myBt < 0 && st0 < KK && st0 + c0 >= KK) {
            myBt = lane * 8 + 2 * i; myM = (int)(st0 + c0);
        }
        if (myBt < 0 && st1 < KK && st1 + c1 >= KK) {
            myBt = lane * 8 + 2 * i + 1; myM = (int)(st1 + c1);
        }
        unsigned packed = st0 | (st1 << 16);
        hist[w][lane * 4 + i] = packed;
        snap[w][lane * 4 + i] = packed;
        run = st1 + c1;
    }
    WB();

    unsigned long long bl = __ballot(myBt >= 0);
    int Bt, m;
    if (bl != 0ull) {
        int src = __ffsll(bl) - 1;
        Bt = __shfl(myBt, src);
        m = __shfl(myM, src);
    } else {
        Bt = NBIN - 1;
        m = 100000;
    }

    if (m <= CAP) {
        // ---- bin-scatter winners into comp (packed atomic slot) ----
        FORALL_VALS({
            int b;
            if (fast) b = (int)((bcache[ci] >> (8 * j)) & 255u);
            else {
                b = (int)(fv * BINSCALE);
                b = b < 0 ? 0 : (b > NBIN - 1 ? NBIN - 1 : b);
            }
            if (b <= Bt) {
                int sh = (b & 1) << 4;
                unsigned old = atomicAdd(&hist[w][b >> 1], 1u << sh);
                int slot = (int)((old >> sh) & 0xFFFFu);
                comp[w][slot] =
                    ((unsigned long long)__float_as_uint(fv) << 32) | (unsigned)e;
            }
        });
        WB();
        // ---- rank pass over compacted slots (<= 4 per lane) ----
        for (int o = lane; o < m; o += 64) {
            unsigned long long key = comp[w][o];
            float fv = __uint_as_float((unsigned)(key >> 32));
            int b = (int)(fv * BINSCALE);
            b = b < 0 ? 0 : (b > NBIN - 1 ? NBIN - 1 : b);
            int sh = (b & 1) << 4;
            unsigned e0 = (hist[w][b >> 1] >> sh) & 0xFFFFu;
            unsigned s0 = (snap[w][b >> 1] >> sh) & 0xFFFFu;
            int r = (int)s0;
            for (unsigned s = s0; s < e0; ++s) r += (comp[w][s] < key);
            if (r < KK) comp2[w][r] = key;
        }
    } else {
        // ---------- rare exact fallback: radix-refine threshold bucket ------
        FORALL_VALS({
            int b = (int)(fv * BINSCALE);
            b = b < 0 ? 0 : (b > NBIN - 1 ? NBIN - 1 : b);
            if (b < Bt) {
                int pos = atomicAdd(&sh_cnt[w], 1);
                if (pos < CAP)
                    comp[w][pos] =
                        ((unsigned long long)__float_as_uint(fv) << 32) | (unsigned)e;
            }
            (void)j; (void)ci;
        });
        WB();
        int nless = sh_cnt[w];
        if (lane == 0) { sh_pref[w] = 0u; sh_kth[w] = KK - nless; }
        WB();
        for (int p = 0; p < 4; ++p) {
#pragma unroll
            for (int i = 0; i < 4; ++i) hist[w][lane * 4 + i] = 0u;
            WB();
            const int shift = 24 - 8 * p;
            const unsigned pref = sh_pref[w];
            FORALL_VALS({
                int b = (int)(fv * BINSCALE);
                b = b < 0 ? 0 : (b > NBIN - 1 ? NBIN - 1 : b);
                if (b == Bt) {
                    unsigned k = __float_as_uint(fv);
                    bool ok = (p == 0) || ((k >> (shift + 8)) == pref);
                    if (ok) atomicAdd(&hist[w][(k >> shift) & 255u], 1u);
                }
                (void)e; (void)j; (void)ci;
            });
            WB();
            if (lane == 0) {
                int kth = sh_kth[w];
                unsigned cum = 0;
                int b = 0;
                for (; b < 256; ++b) {
                    unsigned cc = hist[w][b];
                    if (cum + cc >= (unsigned)kth) break;
                    cum += cc;
                }
                sh_pref[w] = (pref << 8) | (unsigned)b;
                sh_kth[w] = kth - (int)cum;
            }
            WB();
        }
        const unsigned T = sh_pref[w];
        const int need2 = sh_kth[w];
        FORALL_VALS({
            int b = (int)(fv * BINSCALE);
            b = b < 0 ? 0 : (b > NBIN - 1 ? NBIN - 1 : b);
            if (b == Bt) {
                unsigned k = __float_as_uint(fv);
                if (k < T) {
                    int pos = atomicAdd(&sh_cnt[w], 1);
                    if (pos < CAP)
                        comp[w][pos] = ((unsigned long long)k << 32) | (unsigned)e;
                } else if (k == T) {
                    int q = atomicAdd(&sh_ntie[w], 1);
                    if (q < 64) sh_tie[w][q] = e;
                }
            }
            (void)j; (void)ci;
        });
        WB();
        if (lane == 0) {
            int nl2 = sh_cnt[w];
            int nt = sh_ntie[w] < 64 ? sh_ntie[w] : 64;
            for (int i = 1; i < nt; ++i) {
                int v = sh_tie[w][i], j2 = i - 1;
                while (j2 >= 0 && sh_tie[w][j2] > v) {
                    sh_tie[w][j2 + 1] = sh_tie[w][j2];
                    --j2;
                }
                sh_tie[w][j2 + 1] = v;
            }
            for (int i = 0; i < need2; ++i)
                comp[w][nl2 + i] =
                    ((unsigned long long)T << 32) | (unsigned)sh_tie[w][i];
            sh_cnt[w] = nl2 + need2;
        }
        WB();
        const int mm = sh_cnt[w];   // == KK
        for (int o = lane; o < mm; o += 64) {
            unsigned long long key = comp[w][o];
            int r = 0;
            for (int j2 = 0; j2 < mm; ++j2) {
                unsigned long long cj = comp[w][j2];
                r += (cj < key) || (cj == key && j2 < o);
            }
            if (r < KK) comp2[w][r] = key;
        }
    }
    WB();

    // ---- epilogue from comp2 (sorted ascending, rank = index) ----
    const float Tf = __uint_as_float((unsigned)(comp2[w][KK - 1] >> 32));
    const float invT = 1.0f / Tf;
    for (int o = lane; o < KK; o += 64) {
        unsigned long long c = comp2[w][o];
        unsigned kbits = (unsigned)(c >> 32);
        int id = (int)(c & 0xFFFFFFFFu);
        unsigned short nb = bf16rne(__uint_as_float(kbits) * invT);
        xin[(size_t)row * XPAD + o] = nb;
        idxb[(size_t)row * KK + o] = (unsigned short)id;
    }
    if (lane == 0) xin[(size_t)row * XPAD + 200] = bf16rne(scale[row]);
    else if (lane < 24) xin[(size_t)row * XPAD + 200 + lane] = 0;  // zero pad
}

// ---------------------------------------------------------------------------
// Kernel 1b: theta gather, full-throughput (one (row,k) per thread).
// ---------------------------------------------------------------------------
__global__ __launch_bounds__(256) void gather_kernel(
    const float* __restrict__ theta, const unsigned short* __restrict__ idxb,
    unsigned short* __restrict__ xin)
{
    const int i = blockIdx.x * 256 + threadIdx.x;   // exact: M*KK = 6250*256
    const int row = i / KK;
    const int k = i - row * KK;
    const int id = (int)idxb[i];
    float v = theta[(size_t)row * VV + id];
    xin[(size_t)row * XPAD + 100 + k] = bf16rne(v);
}

// ---------------------------------------------------------------------------
// Kernel 2: fused layers 1+2 via MFMA. Block = 64 rows, 4 waves.
// ---------------------------------------------------------------------------
__global__ __launch_bounds__(256) void fused12_mfma(
    const unsigned short* __restrict__ xin, const unsigned short* __restrict__ pw1,
    const float* __restrict__ b1, const unsigned short* __restrict__ pw2,
    const float* __restrict__ b2, unsigned short* __restrict__ h)
{
    __shared__ unsigned short c1s[64][136];
    const int t = threadIdx.x;
    const int w = t >> 6, l = t & 63;
    const int m0 = blockIdx.x * 64;
    const int lr = l & 15, lg = l >> 4;

    f32x4 acc[8] = {};
    const short8* arow = (const short8*)(xin + (size_t)(m0 + 16 * w + lr) * XPAD);
    const short8* pw1v = (const short8*)pw1;
#pragma unroll
    for (int kt = 0; kt < 7; ++kt) {
        short8 a = arow[kt * 4 + lg];
#pragma unroll
        for (int nt = 0; nt < 8; ++nt) {
            short8 b = pw1v[(kt * 8 + nt) * 64 + l];
            acc[nt] = __builtin_amdgcn_mfma_f32_16x16x32_bf16(a, b, acc[nt], 0, 0, 0);
        }
    }
#pragma unroll
    for (int nt = 0; nt < 8; ++nt) {
        int col = nt * 16 + lr;
        float bb = b1[col];
#pragma unroll
        for (int r = 0; r < 4; ++r) {
            float v = fmaxf(acc[nt][r] + bb, 0.f);
            c1s[16 * w + lg * 4 + r][col] = bf16rne(v);
        }
    }
    __syncthreads();

    f32x4 acc2[16] = {};
    const short8* pw2v = (const short8*)pw2;
#pragma unroll
    for (int kt = 0; kt < 4; ++kt) {
        short8 a = *(const short8*)&c1s[16 * w + lr][kt * 32 + lg * 8];
#pragma unroll
        for (int nt = 0; nt < 16; ++nt) {
            short8 b = pw2v[(kt * 16 + nt) * 64 + l];
            acc2[nt] = __builtin_amdgcn_mfma_f32_16x16x32_bf16(a, b, acc2[nt], 0, 0, 0);
        }
    }
#pragma unroll
    for (int nt = 0; nt < 16; ++nt) {
        int col = nt * 16 + lr;
        float bb = b2[col];
#pragma unroll
        for (int r = 0; r < 4; ++r) {
            float v = fmaxf(acc2[nt][r] + bb, 0.f);
            h[(size_t)(m0 + 16 * w + lg * 4 + r) * 256 + col] = bf16rne(v);
        }
    }
}

// ---------------------------------------------------------------------------
// InstanceNorm stats (bf16 h), two-phase, folded affine.
// ---------------------------------------------------------------------------
#define NCHUNK 25
#define CHUNK (NN / NCHUNK)

__global__ __launch_bounds__(256) void stats_partial(
    const unsigned short* __restrict__ h, float* __restrict__ part)
{
    const int b = blockIdx.x, ch = blockIdx.y, c = threadIdx.x;
    const unsigned short* base = h + ((size_t)b * NN + (size_t)ch * CHUNK) * 256 + c;
    float s = 0.f, s2 = 0.f;
    for (int n = 0; n < CHUNK; ++n) {
        float v = bf2f(base[(size_t)n * 256]);
        s += v;
        s2 += v * v;
    }
    size_t o = (((size_t)b * NCHUNK + ch) * 256 + c) * 2;
    part[o] = s;
    part[o + 1] = s2;
}

__global__ __launch_bounds__(256) void stats_final(
    const float* __restrict__ part, const float* __restrict__ gamma,
    const float* __restrict__ beta, float* __restrict__ scv,
    float* __restrict__ shv)
{
    const int b = blockIdx.x, c = threadIdx.x;
    float s = 0.f, s2 = 0.f;
    for (int ch = 0; ch < NCHUNK; ++ch) {
        size_t o = (((size_t)b * NCHUNK + ch) * 256 + c) * 2;
        s += part[o];
        s2 += part[o + 1];
    }
    const float inv = 1.0f / (float)NN;
    float mean = s * inv;
    float var = s2 * inv - mean * mean;
    float rs = rsqrtf(var + 1e-5f);
    float sc = gamma[c] * rs;
    scv[b * 256 + c] = sc;
    shv[b * 256 + c] = beta[c] - mean * sc;
}

// ---------------------------------------------------------------------------
// Kernel 3: fused layers 3+4 + STREAMING output write (bitmap + popcount).
// sdist is read from xin cols [0,100) (identical bf16 values).
// ---------------------------------------------------------------------------
__global__ __launch_bounds__(256) void fused34_mfma(
    const unsigned short* __restrict__ h, const unsigned short* __restrict__ pw3,
    const float* __restrict__ b3, const unsigned short* __restrict__ pw4,
    const float* __restrict__ b4, const float* __restrict__ scv,
    const float* __restrict__ shv, const unsigned short* __restrict__ xin,
    const unsigned short* __restrict__ idxb, float* __restrict__ out)
{
    __shared__ __align__(16) char uni[64 * 100 * 4];      // c1s / valbuf union
    __shared__ __align__(16) unsigned bm[64][64];          // 2048-bit bitmaps
    __shared__ __align__(16) unsigned short wpref[64][64]; // word popcnt prefix
    unsigned short (*c1s)[136] = (unsigned short (*)[136])uni;
    float (*valbuf)[100] = (float (*)[100])uni;

    const int t = threadIdx.x;
    const int w = t >> 6, l = t & 63;
    const int m0 = blockIdx.x * 64;
    const int lr = l & 15, lg = l >> 4;

    // zero bitmaps
    for (int i = t; i < 64 * 64; i += 256) ((unsigned*)bm)[i] = 0u;
    __syncthreads();                                       // S1

    // build bitmaps from idxb (coalesced u16)
    for (int i = t; i < 64 * KK; i += 256) {
        int rrow = i / KK;
        int id = (int)idxb[(size_t)(m0 + rrow) * KK + (i - rrow * KK)];
        atomicOr(&bm[rrow][id >> 5], 1u << (id & 31));
    }

    const int myrow = m0 + 16 * w + lr;
    const int mybatch = myrow / NN;

    // phase 1: norm(h) @ w3, K=256, N=128
    f32x4 acc[8] = {};
    const short8* hrow = (const short8*)(h + (size_t)myrow * 256);
    const short8* pw3v = (const short8*)pw3;
#pragma unroll
    for (int kt = 0; kt < 8; ++kt) {
        int k0 = kt * 32 + lg * 8;
        short8 hv = hrow[kt * 4 + lg];
        const float4* scp = (const float4*)(scv + mybatch * 256 + k0);
        const float4* shp = (const float4*)(shv + mybatch * 256 + k0);
        float4 sc0 = scp[0], sc1 = scp[1];
        float4 sh0 = shp[0], sh1 = shp[1];
        short8 a;
        a[0] = (short)bf16rne(fmaf(bf2f((unsigned short)hv[0]), sc0.x, sh0.x));
        a[1] = (short)bf16rne(fmaf(bf2f((unsigned short)hv[1]), sc0.y, sh0.y));
        a[2] = (short)bf16rne(fmaf(bf2f((unsigned short)hv[2]), sc0.z, sh0.z));
        a[3] = (short)bf16rne(fmaf(bf2f((unsigned short)hv[3]), sc0.w, sh0.w));
        a[4] = (short)bf16rne(fmaf(bf2f((unsigned short)hv[4]), sc1.x, sh1.x));
        a[5] = (short)bf16rne(fmaf(bf2f((unsigned short)hv[5]), sc1.y, sh1.y));
        a[6] = (short)bf16rne(fmaf(bf2f((unsigned short)hv[6]), sc1.z, sh1.z));
        a[7] = (short)bf16rne(fmaf(bf2f((unsigned short)hv[7]), sc1.w, sh1.w));
#pragma unroll
        for (int nt = 0; nt < 8; ++nt) {
            short8 b = pw3v[(kt * 8 + nt) * 64 + l];
            acc[nt] = __builtin_amdgcn_mfma_f32_16x16x32_bf16(a, b, acc[nt], 0, 0, 0);
        }
    }
    __syncthreads();                                       // S2 (bitmap done)

    // word-popcount prefix per row (t<64: one row each)
    if (t < 64) {
        unsigned run = 0;
#pragma unroll
        for (int wd = 0; wd < 63; ++wd) {
            wpref[t][wd] = (unsigned short)run;
            run += (unsigned)__popc(bm[t][wd]);
        }
        wpref[t][63] = (unsigned short)run;
    }

#pragma unroll
    for (int nt = 0; nt < 8; ++nt) {
        int col = nt * 16 + lr;
        float bb = b3[col];
#pragma unroll
        for (int r = 0; r < 4; ++r) {
            float v = fmaxf(acc[nt][r] + bb, 0.f);
            c1s[16 * w + lg * 4 + r][col] = bf16rne(v);
        }
    }
    __syncthreads();                                       // S3

    // phase 2: @ w4, K=128, N=112 (cols 100..111 zero weights)
    f32x4 acc2[7] = {};
    const short8* pw4v = (const short8*)pw4;
#pragma unroll
    for (int kt = 0; kt < 4; ++kt) {
        short8 a = *(const short8*)&c1s[16 * w + lr][kt * 32 + lg * 8];
#pragma unroll
        for (int nt = 0; nt < 7; ++nt) {
            short8 b = pw4v[(kt * 7 + nt) * 64 + l];
            acc2[nt] = __builtin_amdgcn_mfma_f32_16x16x32_bf16(a, b, acc2[nt], 0, 0, 0);
        }
    }
    __syncthreads();                                       // S4 (c1s dead)

    // epilogue: +b4 - sdist(from xin), place into valbuf at index-order rank
#pragma unroll
    for (int nt = 0; nt < 7; ++nt) {
        int col = nt * 16 + lr;
        if (col < KK) {
            float bb = b4[col];
#pragma unroll
            for (int r = 0; r < 4; ++r) {
                int r4 = 16 * w + lg * 4 + r;
                int mrow = m0 + r4;
                float v = acc2[nt][r] + bb -
                          bf2f(xin[(size_t)mrow * XPAD + col]);
                int id = (int)idxb[(size_t)mrow * KK + col];
                int wd = id >> 5;
                int irank = (int)wpref[r4][wd] +
                            __popc(bm[r4][wd] & ((1u << (id & 31)) - 1u));
                valbuf[r4][irank] = v;
            }
        }
    }
    __syncthreads();                                       // S5

    // streaming write: 64 rows x 500 float4, fully coalesced, no RFO
    for (int i = t; i < 64 * (VV / 4); i += 256) {
        int rrow = i / (VV / 4);
        int p = i - rrow * (VV / 4);
        int v0 = p * 4;
        unsigned word = bm[rrow][v0 >> 5];
        int sh = v0 & 31;
        int racc = (int)wpref[rrow][v0 >> 5] + __popc(word & ((1u << sh) - 1u));
        float4 o;
        unsigned b0 = (word >> sh) & 1u;
        o.x = b0 ? valbuf[rrow][racc] : PENALTY; racc += b0;
        unsigned b1_ = (word >> (sh + 1)) & 1u;
        o.y = b1_ ? valbuf[rrow][racc] : PENALTY; racc += b1_;
        unsigned b2_ = (word >> (sh + 2)) & 1u;
        o.z = b2_ ? valbuf[rrow][racc] : PENALTY; racc += b2_;
        unsigned b3_ = (word >> (sh + 3)) & 1u;
        o.w = b3_ ? valbuf[rrow][racc] : PENALTY;
        ((float4*)(out + (size_t)(m0 + rrow) * VV))[p] = o;
    }
}

extern "C" void kernel_launch(void* const* d_in, const int* in_sizes, int n_in,
                              void* d_out, int out_size, void* d_ws, size_t ws_size,
                              hipStream_t stream)
{
    const float* dist  = (const float*)d_in[0];
    const float* theta = (const float*)d_in[1];
    const float* scale = (const float*)d_in[2];
    const float* w1 = (const float*)d_in[3];
    const float* b1 = (const float*)d_in[4];
    const float* w2 = (const float*)d_in[5];
    const float* b2 = (const float*)d_in[6];
    const float* w3 = (const float*)d_in[7];
    const float* b3 = (const float*)d_in[8];
    const float* w4 = (const float*)d_in[9];
    const float* b4 = (const float*)d_in[10];
    const float* gamma = (const float*)d_in[11];
    const float* beta  = (const float*)d_in[12];
    float* out = (float*)d_out;

    const int M = BB * NN;  // 16000

    char* p = (char*)d_ws;
    unsigned short* xin   = (unsigned short*)p;     p += (size_t)M * XPAD * 2;
    unsigned short* h     = (unsigned short*)p;     p += (size_t)M * 256 * 2;
    unsigned short* idxb  = (unsigned short*)p;     p += (size_t)M * KK * 2;
    float* part  = (float*)p;                       p += (size_t)BB * NCHUNK * 256 * 2 * 4;
    float* scv   = (float*)p;                       p += 8 * 256 * 4;
    float* shv   = (float*)p;                       p += 8 * 256 * 4;
    unsigned short* pw1 = (unsigned short*)p;       p += 56 * 512 * 2;
    unsigned short* pw2 = (unsigned short*)p;       p += 64 * 512 * 2;
    unsigned short* pw3 = (unsigned short*)p;       p += 64 * 512 * 2;
    unsigned short* pw4 = (unsigned short*)p;       p += 28 * 512 * 2;

    topk_kernel<<<NWPACK + TOPKB, 256, 0, stream>>>(
        dist, scale, xin, idxb,
        w1, w2, w3, w4, pw1, pw2, pw3, pw4);

    gather_kernel<<<(M * KK) / 256, 256, 0, stream>>>(theta, idxb, xin);

    fused12_mfma<<<M / 64, 256, 0, stream>>>(xin, pw1, b1, pw2, b2, h);

    stats_partial<<<dim3(BB, NCHUNK), 256, 0, stream>>>(h, part);
    stats_final<<<BB, 256, 0, stream>>>(part, gamma, beta, scv, shv);

    fused34_mfma<<<M / 64, 256, 0, stream>>>(h, pw3, b3, pw4, b4, scv, shv,
                                             xin, idxb, out);
}